// Round 1
// baseline (239.825 us; speedup 1.0000x reference)
//
#include <hip/hip_runtime.h>
#include <math.h>

// Lower-triangle flat index, j <= i
#define LT(i,j) ((i)*((i)+1)/2 + (j))

// In-place Cholesky (lower) of a 6x6 SPD matrix stored as packed lower triangle (21 floats).
__device__ __forceinline__ void chol6(float* a) {
  #pragma unroll
  for (int j = 0; j < 6; ++j) {
    float d = a[LT(j,j)];
    #pragma unroll
    for (int p = 0; p < j; ++p) d -= a[LT(j,p)] * a[LT(j,p)];
    d = sqrtf(d);
    const float rd = 1.0f / d;
    a[LT(j,j)] = d;
    #pragma unroll
    for (int i = j + 1; i < 6; ++i) {
      float s = a[LT(i,j)];
      #pragma unroll
      for (int p = 0; p < j; ++p) s -= a[LT(i,p)] * a[LT(j,p)];
      a[LT(i,j)] = s * rd;
    }
  }
}

// In-place inverse of a lower-triangular 6x6 (packed lower triangle, 21 floats).
// Column-major processing: when computing M[i][j], L[i][p] (p>=j, col>j) not yet
// overwritten; M[p][j] (p<i) already written. Safe in place.
__device__ __forceinline__ void trinv6(float* a) {
  #pragma unroll
  for (int j = 0; j < 6; ++j) {
    const float mjj = 1.0f / a[LT(j,j)];
    a[LT(j,j)] = mjj;
    #pragma unroll
    for (int i = j + 1; i < 6; ++i) {
      float s = 0.0f;
      #pragma unroll
      for (int p = j; p < i; ++p) s += a[LT(i,p)] * a[LT(p,j)];
      a[LT(i,j)] = -s / a[LT(i,i)];
    }
  }
}

template <int R>
__global__ __launch_bounds__(256)
void cca_kernel(const float* __restrict__ xg, const float* __restrict__ yg,
                float* __restrict__ out, const int ri) {
  constexpr int H = 512, W = 512, C = 6;
  constexpr int K = 2 * R + 1;
  constexpr int T = 16;          // 16x16 output tile
  constexpr int S = T + 2 * R;   // padded tile extent
  constexpr int SP = S + 1;      // +1 col pad (2-way LDS conflicts are free)

  __shared__ float lsx[C][S][SP];
  __shared__ float lsy[C][S][SP];

  const int b   = blockIdx.z;
  const int h0  = blockIdx.y * T;
  const int w0  = blockIdx.x * T;
  const int tid = threadIdx.x;

  // Stage reflect-padded x/y tiles into LDS (coalesced along col for interior).
  for (int i = tid; i < C * S * S; i += 256) {
    const int ch  = i / (S * S);
    const int rem = i - ch * (S * S);
    const int row = rem / S;
    const int col = rem - row * S;
    int h = h0 - R + row; h = (h < 0) ? -h : ((h >= H) ? (2 * H - 2 - h) : h);
    int w = w0 - R + col; w = (w < 0) ? -w : ((w >= W) ? (2 * W - 2 - w) : w);
    const int gi = ((b * C + ch) * H + h) * W + w;
    lsx[ch][row][col] = xg[gi];
    lsy[ch][row][col] = yg[gi];
  }
  __syncthreads();

  const int ty = tid >> 4;
  const int tx = tid & 15;

  float sx[6]   = {0, 0, 0, 0, 0, 0};
  float sy[6]   = {0, 0, 0, 0, 0, 0};
  float sxx[21] = {0};
  float syy[21] = {0};
  float sxy[36] = {0};

  #pragma unroll 1   // keep dy as a real loop: dx body is ~1k inst already
  for (int dy = 0; dy < K; ++dy) {
    #pragma unroll
    for (int dx = 0; dx < K; ++dx) {
      float xv[6], yv[6];
      #pragma unroll
      for (int c = 0; c < 6; ++c) {
        xv[c] = lsx[c][ty + dy][tx + dx];
        yv[c] = lsy[c][ty + dy][tx + dx];
      }
      #pragma unroll
      for (int c = 0; c < 6; ++c) { sx[c] += xv[c]; sy[c] += yv[c]; }
      int t = 0;
      #pragma unroll
      for (int i2 = 0; i2 < 6; ++i2) {
        #pragma unroll
        for (int j = 0; j <= i2; ++j) {
          sxx[t] += xv[i2] * xv[j];
          syy[t] += yv[i2] * yv[j];
          ++t;
        }
      }
      #pragma unroll
      for (int i2 = 0; i2 < 6; ++i2) {
        #pragma unroll
        for (int j = 0; j < 6; ++j) sxy[i2 * 6 + j] += xv[i2] * yv[j];
      }
    }
  }

  // Moments -> covariances (in place to keep VGPR pressure down).
  constexpr float inv_n = 1.0f / (K * K);
  float mx[6], my[6];
  #pragma unroll
  for (int i = 0; i < 6; ++i) { mx[i] = sx[i] * inv_n; my[i] = sy[i] * inv_n; }
  {
    int t = 0;
    #pragma unroll
    for (int i = 0; i < 6; ++i) {
      #pragma unroll
      for (int j = 0; j <= i; ++j) {
        const float e = (i == j) ? 1e-6f : 0.0f;
        sxx[t] = sxx[t] * inv_n - mx[i] * mx[j] + e;
        syy[t] = syy[t] * inv_n - my[i] * my[j] + e;
        ++t;
      }
    }
  }
  #pragma unroll
  for (int i = 0; i < 6; ++i) {
    #pragma unroll
    for (int j = 0; j < 6; ++j) sxy[i * 6 + j] = sxy[i * 6 + j] * inv_n - mx[i] * my[j];
  }

  chol6(sxx); trinv6(sxx);  // sxx = Mx = Lx^{-1} (lower)
  chol6(syy); trinv6(syy);  // syy = My = Ly^{-1} (lower)

  // diag_i = sum_{j<=i} Mx[i][j] * ( sum_{k>=i} Cxy[j][k] * My[k][i] )
  float sim = 0.0f;
  #pragma unroll
  for (int i = 0; i < 6; ++i) {
    float di = 0.0f;
    #pragma unroll
    for (int j = 0; j <= i; ++j) {
      float inner = 0.0f;
      #pragma unroll
      for (int k2 = i; k2 < 6; ++k2) inner += sxy[j * 6 + k2] * syy[LT(k2, i)];
      di += sxx[LT(i, j)] * inner;
    }
    sim += fabsf(di);
  }
  sim *= (1.0f / 6.0f);

  const int h = h0 + ty;
  const int w = w0 + tx;
  out[(size_t)((b * H + h) * W + w) * 2 + ri] = sim;
}

extern "C" void kernel_launch(void* const* d_in, const int* in_sizes, int n_in,
                              void* d_out, int out_size, void* d_ws, size_t ws_size,
                              hipStream_t stream) {
  const float* x = (const float*)d_in[0];
  const float* y = (const float*)d_in[1];
  float* out = (float*)d_out;
  dim3 grid(512 / 16, 512 / 16, 2);  // (W tiles, H tiles, B)
  cca_kernel<2><<<grid, dim3(256), 0, stream>>>(x, y, out, 0);
  cca_kernel<4><<<grid, dim3(256), 0, stream>>>(x, y, out, 1);
}